// Round 7
// baseline (733.808 us; speedup 1.0000x reference)
//
#include <hip/hip_runtime.h>

#define TSTEPS 12
#define NNODES 50000
#define DIN 32
#define HDIM 128
#define DECS 7
#define MTILE 64
#define NRT 4                                   // row-tiles of 16
#define NTILES ((NNODES + MTILE - 1) / MTILE)   // 782

#define HS 140     // halves/row: measured ZERO bank conflicts (r5/r6)
#define XS 34      // halves/row per timestep of x tile (17-dw stride, odd -> conflict-light)
#define XSLOTS 3   // rolling x buffer

typedef _Float16 half_t;
typedef _Float16 half8 __attribute__((ext_vector_type(8)));
typedef _Float16 half4_ __attribute__((ext_vector_type(4)));
typedef float float4_ __attribute__((ext_vector_type(4)));

#define WS_FLOAT_OFF 548864

#if __has_builtin(__builtin_amdgcn_exp2f)
#define EXP2F __builtin_amdgcn_exp2f
#else
#define EXP2F exp2f
#endif
#if __has_builtin(__builtin_amdgcn_rcpf)
#define RCPF __builtin_amdgcn_rcpf
#else
#define RCPF(x) (1.0f / (x))
#endif

#define K_LOG2E 1.44269504f

__device__ __forceinline__ float sigmoidf_(float x) {
    return RCPF(1.0f + EXP2F(-K_LOG2E * x));
}
// sigma(a) * tanh(b) with ONE rcp: (e^{2b}-1) / [(1+e^{-a})(e^{2b}+1)]
__device__ __forceinline__ float sig_mul_tanh(float a, float b) {
    float ea  = EXP2F(-K_LOG2E * a);
    float tb  = EXP2F(2.0f * K_LOG2E * b);
    float tp1 = tb + 1.0f;
    return (tb - 1.0f) * RCPF(fmaf(ea, tp1, tp1));
}

// Pack fp32 [R,C] row-major into fragment-major fp16 (B-operand layout):
// dst[((ct*KB+kb)*64 + lane)*8 + j] = src[ct*16 + (lane&15)][kb*32 + (lane>>4)*8 + j]
__global__ void pack_weights_k(const float* __restrict__ src, half_t* __restrict__ dst,
                               int C, int KB, int total) {
    int tid = blockIdx.x * blockDim.x + threadIdx.x;
    if (tid >= total) return;
    int j    = tid & 7;
    int lane = (tid >> 3) & 63;
    int rest = tid >> 9;
    int kb   = rest % KB;
    int ct   = rest / KB;
    int row  = ct * 16 + (lane & 15);
    int col  = kb * 32 + ((lane >> 4) << 3) + j;
    dst[tid] = (half_t)src[row * C + col];
}

__global__ void prep_bias_k(const float* __restrict__ bih_e, const float* __restrict__ bhh_e,
                            const float* __restrict__ bih_d, const float* __restrict__ bhh_d,
                            float* __restrict__ be, float* __restrict__ bd) {
    int tid = blockIdx.x * blockDim.x + threadIdx.x;
    if (tid < 512) {
        be[tid] = bih_e[tid] + bhh_e[tid];
        bd[tid] = bih_d[tid] + bhh_d[tid];
    }
}

// Stage one timestep of x (64 rows x 32 cols, fp32->fp16) into xa slot t%3.
__device__ __forceinline__ void stage_x(const float* __restrict__ x, half_t* __restrict__ xa,
                                        int t, int n0, int tid) {
    if (tid < MTILE * 4) {
        int row = tid >> 2;
        int c0  = (tid & 3) * 8;
        int n   = n0 + row;
        float4_ a0 = {0.f, 0.f, 0.f, 0.f}, a1 = {0.f, 0.f, 0.f, 0.f};
        if (n < NNODES) {
            const float* p = x + ((size_t)t * NNODES + n) * DIN + c0;
            a0 = *(const float4_*)p;
            a1 = *(const float4_*)(p + 4);
        }
        half8 hv;
        hv[0] = (half_t)a0[0]; hv[1] = (half_t)a0[1]; hv[2] = (half_t)a0[2]; hv[3] = (half_t)a0[3];
        hv[4] = (half_t)a1[0]; hv[5] = (half_t)a1[1]; hv[6] = (half_t)a1[2]; hv[7] = (half_t)a1[3];
        *(half8*)(xa + ((t % XSLOTS) * MTILE + row) * XS + c0) = hv;
    }
}

// Gate nonlinearity + cell update (C-layout h write). 8 trans ops/element.
__device__ __forceinline__ void cell_update(
    const float4_ acc[4], float cS[4], half_t* __restrict__ hOut,
    int rt, int w, int q, int l15) {
#pragma unroll
    for (int r = 0; r < 4; ++r) {
        float sf = sigmoidf_(acc[1][r]);
        float ig = sig_mul_tanh(acc[0][r], acc[2][r]);   // sigma(i)*tanh(g)
        float c  = fmaf(sf, cS[r], ig);
        cS[r] = c;
        float h = sig_mul_tanh(acc[3][r], c);            // sigma(o)*tanh(c)
        hOut[(rt * 16 + q * 4 + r) * HS + w * 16 + l15] = (half_t)h;
    }
}

// CRITICAL-PATH step: z = zxe (precomputed e-side, fp16 regs) + h@Whh^T.
// MFMA chain depth 4 (was 8). Wave w owns z cols [16w,16w+16)/gate.
__device__ __forceinline__ void lstm_h_step(
    const half_t* __restrict__ hA, half_t* __restrict__ hOut,
    const half8 (&wfh)[4][4], const half4_ (&zxe)[4][NRT],
    float cS[NRT][4], int w, int q, int l15) {
#pragma unroll
    for (int rt = 0; rt < NRT; ++rt) {
        float4_ acc[4];
#pragma unroll
        for (int g = 0; g < 4; ++g)
#pragma unroll
            for (int r = 0; r < 4; ++r) acc[g][r] = (float)zxe[g][rt][r];
#pragma unroll
        for (int kb = 0; kb < 4; ++kb) {
            half8 ah = *(const half8*)(hA + (rt * 16 + l15) * HS + kb * 32 + q * 8);
#pragma unroll
            for (int g = 0; g < 4; ++g)
                acc[g] = __builtin_amdgcn_mfma_f32_16x16x32_f16(ah, wfh[g][kb], acc[g], 0, 0, 0);
        }
        cell_update(acc, cS[rt], hOut, rt, w, q, l15);
    }
}

// OFF-PATH: zxe = inA@W^T + b (A-layout read from LDS), result to fp16 regs.
__device__ __forceinline__ void zxe_compute(
    const half_t* __restrict__ inA, const half8 (&wf)[4][4], const float bR[4],
    half4_ (&zxe)[4][NRT], int q, int l15) {
#pragma unroll
    for (int rt = 0; rt < NRT; ++rt) {
        float4_ acc[4];
#pragma unroll
        for (int g = 0; g < 4; ++g) {
            float b = bR[g];
            acc[g][0] = b; acc[g][1] = b; acc[g][2] = b; acc[g][3] = b;
        }
#pragma unroll
        for (int kb = 0; kb < 4; ++kb) {
            half8 ae = *(const half8*)(inA + (rt * 16 + l15) * HS + kb * 32 + q * 8);
#pragma unroll
            for (int g = 0; g < 4; ++g)
                acc[g] = __builtin_amdgcn_mfma_f32_16x16x32_f16(ae, wf[g][kb], acc[g], 0, 0, 0);
        }
#pragma unroll
        for (int g = 0; g < 4; ++g)
#pragma unroll
            for (int r = 0; r < 4; ++r) zxe[g][rt][r] = (half_t)acc[g][r];
    }
}

// OFF-PATH: e_t = relu(x_t @ encW^T + enc_b); wave w -> e cols [16w,16w+16)
__device__ __forceinline__ void enc_proj(
    const half_t* __restrict__ xa, half_t* __restrict__ eOut,
    half8 encWf, float benc, int t, int w, int q, int l15) {
    const half_t* xs = xa + (t % XSLOTS) * MTILE * XS;
#pragma unroll
    for (int rt = 0; rt < NRT; ++rt) {
        half8 af = *(const half8*)(xs + (rt * 16 + l15) * XS + q * 8);
        float4_ a;
        a[0] = benc; a[1] = benc; a[2] = benc; a[3] = benc;
        a = __builtin_amdgcn_mfma_f32_16x16x32_f16(af, encWf, a, 0, 0, 0);
#pragma unroll
        for (int r = 0; r < 4; ++r) {
            float v = a[r];
            v = v > 0.f ? v : 0.f;
            eOut[(rt * 16 + q * 4 + r) * HS + w * 16 + l15] = (half_t)v;
        }
    }
}

__global__ __launch_bounds__(512, 2) void seq2seq_main_k(
    const float* __restrict__ x,
    const float* __restrict__ enc_b,
    const float* __restrict__ fc1_b,
    const float* __restrict__ fc2_W,
    const float* __restrict__ fc2_b,
    const half_t* __restrict__ wsh,
    const float* __restrict__ be,
    const float* __restrict__ bd,
    float* __restrict__ out) {
    __shared__ __align__(16) half_t xa[XSLOTS * MTILE * XS];   // 13056 B
    __shared__ __align__(16) half_t e_lds[2][MTILE * HS];      // 35840 B
    __shared__ __align__(16) half_t h_lds[2][MTILE * HS];      // 35840 B
    __shared__ float pred_lds[4][MTILE];                       // 1024 B  -> ~86 KB

    const int tid  = threadIdx.x;
    const int lane = tid & 63;
    const int w    = tid >> 6;        // wave 0..7
    const int q    = lane >> 4;
    const int l15  = lane & 15;
    const int n0   = blockIdx.x * MTILE;

    const half_t* WihE  = wsh;
    const half_t* WhhE  = wsh + 65536;
    const half_t* WihD  = wsh + 131072;
    const half_t* WhhD  = wsh + 196608;
    const half_t* encWp = wsh + 262144;
    const half_t* fc1p  = wsh + 266240;

    float beR[4];
#pragma unroll
    for (int g = 0; g < 4; ++g) beR[g] = be[g * 128 + w * 16 + l15];
    float benc = enc_b[w * 16 + l15];

    // prime rolling x buffer
    stage_x(x, xa, 0, n0, tid);
    stage_x(x, xa, 1, n0, tid);
    stage_x(x, xa, 2, n0, tid);

    // zero initial h
    for (int i = tid; i < MTILE * HS; i += 512) h_lds[0][i] = (half_t)0.0f;

    float c_reg[NRT][4];
#pragma unroll
    for (int rt = 0; rt < NRT; ++rt)
#pragma unroll
        for (int r = 0; r < 4; ++r) c_reg[rt][r] = 0.0f;

    // encoder weights into registers (128 VGPR/wave)
    half8 wfi[4][4], wfh[4][4];
#pragma unroll
    for (int g = 0; g < 4; ++g)
#pragma unroll
        for (int kb = 0; kb < 4; ++kb) {
            int ct = g * 8 + w;
            wfi[g][kb] = *(const half8*)(WihE + ((size_t)(ct * 4 + kb) * 64 + lane) * 8);
            wfh[g][kb] = *(const half8*)(WhhE + ((size_t)(ct * 4 + kb) * 64 + lane) * 8);
        }
    half8 encWf = *(const half8*)(encWp + (size_t)w * 512 + lane * 8);

    __syncthreads();  // xa(0..2) + h0 ready

    enc_proj(xa, e_lds[0], encWf, benc, 0, w, q, l15);
    enc_proj(xa, e_lds[1], encWf, benc, 1, w, q, l15);
    __syncthreads();  // e0, e1 ready

    half4_ zxe[4][NRT];
    zxe_compute(e_lds[0], wfi, beR, zxe, q, l15);  // z_e(0)
    stage_x(x, xa, 3, n0, tid);                    // slot 0 (x0 dead)
    __syncthreads();

    int cur = 0;
    // ================= encoder: one barrier per iter =================
    for (int t = 0; t < TSTEPS; ++t) {
        // A (critical): h(t+1) from zxe(t) + h(t)@Whh
        lstm_h_step(h_lds[cur], h_lds[cur ^ 1], wfh, zxe, c_reg, w, q, l15);
        // B (off-path): zxe(t+1) from e(t+1)
        if (t + 1 < TSTEPS)
            zxe_compute(e_lds[(t + 1) & 1], wfi, beR, zxe, q, l15);
        // C (off-path): e(t+2) from xa
        if (t + 2 < TSTEPS)
            enc_proj(xa, e_lds[t & 1], encWf, benc, t + 2, w, q, l15);
        // D (off-path): stage x(t+4)
        if (t + 4 < TSTEPS)
            stage_x(x, xa, t + 4, n0, tid);
        __syncthreads();
        cur ^= 1;
    }
    // cur == 0; h_lds[0] = final encoder h = d_in; c_reg = final encoder c

    // ---- decoder transition: zx_dec = d_in@WihD^T + b_d (wfi reused, then dead) ----
#pragma unroll
    for (int g = 0; g < 4; ++g)
#pragma unroll
        for (int kb = 0; kb < 4; ++kb) {
            int ct = g * 8 + w;
            wfi[g][kb] = *(const half8*)(WihD + ((size_t)(ct * 4 + kb) * 64 + lane) * 8);
        }
    {
        float bdR[4];
#pragma unroll
        for (int g = 0; g < 4; ++g) bdR[g] = bd[g * 128 + w * 16 + l15];
        zxe_compute(h_lds[cur], wfi, bdR, zxe, q, l15);
    }
    // wfi dead -> decoder recurrent weights + head params
#pragma unroll
    for (int g = 0; g < 4; ++g)
#pragma unroll
        for (int kb = 0; kb < 4; ++kb) {
            int ct = g * 8 + w;
            wfh[g][kb] = *(const half8*)(WhhD + ((size_t)(ct * 4 + kb) * 64 + lane) * 8);
        }
    half8 fc1f[4];
#pragma unroll
    for (int kb = 0; kb < 4; ++kb)
        fc1f[kb] = *(const half8*)(fc1p + ((size_t)((w & 3) * 4 + kb) * 64 + lane) * 8);
    float bf1 = fc1_b[(w & 3) * 16 + l15];
    float wf2 = fc2_W[(w & 3) * 16 + l15];
    float bf2 = fc2_b[0];
    const int rtH = (w >> 2) * 2;   // head row-tiles per wave: {rtH, rtH+1}

    // ================= decoder =================
    for (int s = 0; s < DECS; ++s) {
        lstm_h_step(h_lds[cur], h_lds[cur ^ 1], wfh, zxe, c_reg, w, q, l15);
        cur ^= 1;
        __syncthreads();  // new h ready
        // head: o64 = relu(h @ fc1^T + b1); pred = o64 @ fc2^T + b2
#pragma unroll
        for (int rp = 0; rp < 2; ++rp) {
            int rt = rtH + rp;
            float4_ hacc;
            hacc[0] = bf1; hacc[1] = bf1; hacc[2] = bf1; hacc[3] = bf1;
#pragma unroll
            for (int kb = 0; kb < 4; ++kb) {
                half8 af = *(const half8*)(h_lds[cur] + (rt * 16 + l15) * HS + kb * 32 + q * 8);
                hacc = __builtin_amdgcn_mfma_f32_16x16x32_f16(af, fc1f[kb], hacc, 0, 0, 0);
            }
#pragma unroll
            for (int r = 0; r < 4; ++r) {
                float v = hacc[r];
                v = v > 0.f ? v : 0.f;
                v *= wf2;
                v += __shfl_xor(v, 1, 64);
                v += __shfl_xor(v, 2, 64);
                v += __shfl_xor(v, 4, 64);
                v += __shfl_xor(v, 8, 64);
                if (l15 == 0) pred_lds[w & 3][rt * 16 + q * 4 + r] = v;
            }
        }
        __syncthreads();
        if (tid < MTILE) {
            float sum = pred_lds[0][tid] + pred_lds[1][tid] + pred_lds[2][tid] + pred_lds[3][tid] + bf2;
            int n = n0 + tid;
            if (n < NNODES) out[(size_t)n * DECS + s] = sum;
        }
        // pred_lds(s+1) writes are ordered behind the next lstm step's barrier
    }
}

extern "C" void kernel_launch(void* const* d_in, const int* in_sizes, int n_in,
                              void* d_out, int out_size, void* d_ws, size_t ws_size,
                              hipStream_t stream) {
    (void)in_sizes; (void)n_in; (void)out_size; (void)ws_size;
    const float* x     = (const float*)d_in[0];
    const float* enc_W = (const float*)d_in[1];
    const float* enc_b = (const float*)d_in[2];
    const float* Wih_e = (const float*)d_in[3];
    const float* Whh_e = (const float*)d_in[4];
    const float* bih_e = (const float*)d_in[5];
    const float* bhh_e = (const float*)d_in[6];
    const float* Wih_d = (const float*)d_in[7];
    const float* Whh_d = (const float*)d_in[8];
    const float* bih_d = (const float*)d_in[9];
    const float* bhh_d = (const float*)d_in[10];
    const float* fc1_W = (const float*)d_in[11];
    const float* fc1_b = (const float*)d_in[12];
    const float* fc2_W = (const float*)d_in[13];
    const float* fc2_b = (const float*)d_in[14];

    half_t* wsh = (half_t*)d_ws;
    float*  be  = (float*)((char*)d_ws + WS_FLOAT_OFF);
    float*  bd  = be + 512;

    pack_weights_k<<<256, 256, 0, stream>>>(Wih_e, wsh + 0,      128, 4, 65536);
    pack_weights_k<<<256, 256, 0, stream>>>(Whh_e, wsh + 65536,  128, 4, 65536);
    pack_weights_k<<<256, 256, 0, stream>>>(Wih_d, wsh + 131072, 128, 4, 65536);
    pack_weights_k<<<256, 256, 0, stream>>>(Whh_d, wsh + 196608, 128, 4, 65536);
    pack_weights_k<<<16,  256, 0, stream>>>(enc_W, wsh + 262144, 32,  1, 4096);
    pack_weights_k<<<32,  256, 0, stream>>>(fc1_W, wsh + 266240, 128, 4, 8192);
    prep_bias_k<<<2, 256, 0, stream>>>(bih_e, bhh_e, bih_d, bhh_d, be, bd);

    seq2seq_main_k<<<NTILES, 512, 0, stream>>>(x, enc_b, fc1_b, fc2_W, fc2_b,
                                               wsh, be, bd, (float*)d_out);
}

// Round 8
// 712.536 us; speedup vs baseline: 1.0299x; 1.0299x over previous
//
#include <hip/hip_runtime.h>

#define TSTEPS 12
#define NNODES 50000
#define DIN 32
#define HDIM 128
#define DECS 7
#define MTILE 112
#define NRT 7                                   // row-tiles of 16
#define NTILES ((NNODES + MTILE - 1) / MTILE)   // 447 -> 1.75 rounds/CU, ~12.5% tail (best grid)

#define HS 140     // halves/row: measured ZERO bank conflicts (r5/r6/r7)
#define XS 36      // halves/row per timestep of x tile (r6-measured conflict-free)
#define XSLOTS 2   // rolling x buffer: stage t+2 during iter t

typedef _Float16 half_t;
typedef _Float16 half8 __attribute__((ext_vector_type(8)));
typedef float float4_ __attribute__((ext_vector_type(4)));

#define WS_FLOAT_OFF 548864

#if __has_builtin(__builtin_amdgcn_exp2f)
#define EXP2F __builtin_amdgcn_exp2f
#else
#define EXP2F exp2f
#endif
#if __has_builtin(__builtin_amdgcn_rcpf)
#define RCPF __builtin_amdgcn_rcpf
#else
#define RCPF(x) (1.0f / (x))
#endif

#define K_LOG2E 1.44269504f

__device__ __forceinline__ float sigmoidf_(float x) {
    return RCPF(1.0f + EXP2F(-K_LOG2E * x));
}
// sigma(a) * tanh(b) with ONE rcp: (e^{2b}-1) / [(1+e^{-a})(e^{2b}+1)]  (r6-validated numerics)
__device__ __forceinline__ float sig_mul_tanh(float a, float b) {
    float ea  = EXP2F(-K_LOG2E * a);
    float tb  = EXP2F(2.0f * K_LOG2E * b);
    float tp1 = tb + 1.0f;
    return (tb - 1.0f) * RCPF(fmaf(ea, tp1, tp1));
}

// Pack fp32 [R,C] row-major into fragment-major fp16 (B-operand layout):
// dst[((ct*KB+kb)*64 + lane)*8 + j] = src[ct*16 + (lane&15)][kb*32 + (lane>>4)*8 + j]
__global__ void pack_weights_k(const float* __restrict__ src, half_t* __restrict__ dst,
                               int C, int KB, int total) {
    int tid = blockIdx.x * blockDim.x + threadIdx.x;
    if (tid >= total) return;
    int j    = tid & 7;
    int lane = (tid >> 3) & 63;
    int rest = tid >> 9;
    int kb   = rest % KB;
    int ct   = rest / KB;
    int row  = ct * 16 + (lane & 15);
    int col  = kb * 32 + ((lane >> 4) << 3) + j;
    dst[tid] = (half_t)src[row * C + col];
}

__global__ void prep_bias_k(const float* __restrict__ bih_e, const float* __restrict__ bhh_e,
                            const float* __restrict__ bih_d, const float* __restrict__ bhh_d,
                            float* __restrict__ be, float* __restrict__ bd) {
    int tid = blockIdx.x * blockDim.x + threadIdx.x;
    if (tid < 512) {
        be[tid] = bih_e[tid] + bhh_e[tid];
        bd[tid] = bih_d[tid] + bhh_d[tid];
    }
}

// Stage one timestep of x (112 rows x 32 cols, fp32->fp16) into xa slot t&1.
__device__ __forceinline__ void stage_x(const float* __restrict__ x, half_t* __restrict__ xa,
                                        int t, int n0, int tid) {
    if (tid < MTILE * 4) {
        int row = tid >> 2;
        int c0  = (tid & 3) * 8;
        int n   = n0 + row;
        float4_ a0 = {0.f, 0.f, 0.f, 0.f}, a1 = {0.f, 0.f, 0.f, 0.f};
        if (n < NNODES) {
            const float* p = x + ((size_t)t * NNODES + n) * DIN + c0;
            a0 = *(const float4_*)p;
            a1 = *(const float4_*)(p + 4);
        }
        half8 hv;
        hv[0] = (half_t)a0[0]; hv[1] = (half_t)a0[1]; hv[2] = (half_t)a0[2]; hv[3] = (half_t)a0[3];
        hv[4] = (half_t)a1[0]; hv[5] = (half_t)a1[1]; hv[6] = (half_t)a1[2]; hv[7] = (half_t)a1[3];
        *(half8*)(xa + ((t & 1) * MTILE + row) * XS + c0) = hv;
    }
}

// Gate nonlinearity + cell update (C-layout h write). 8 trans ops/element.
__device__ __forceinline__ void cell_update(
    const float4_ acc[4], float cS[4], half_t* __restrict__ hOut,
    int rt, int w, int q, int l15) {
#pragma unroll
    for (int r = 0; r < 4; ++r) {
        float sf = sigmoidf_(acc[1][r]);
        float ig = sig_mul_tanh(acc[0][r], acc[2][r]);   // sigma(i)*tanh(g)
        float c  = fmaf(sf, cS[r], ig);
        cS[r] = c;
        float h = sig_mul_tanh(acc[3][r], c);            // sigma(o)*tanh(c)
        hOut[(rt * 16 + q * 4 + r) * HS + w * 16 + l15] = (half_t)h;
    }
}

// Fused LSTM step (r4 skeleton): z = e@Wih^T + h@Whh^T + b, all in one pass.
// Wave w owns z cols [16w,16w+16)/gate. 16 independent acc chains (4 gates x NRT rts).
__device__ __forceinline__ void lstm_step(
    const half_t* __restrict__ eA, const half_t* __restrict__ hA, half_t* __restrict__ hOut,
    const half8 (&wfi)[4][4], const half8 (&wfh)[4][4],
    const float bR[4], float cS[NRT][4],
    int w, int q, int l15) {
#pragma unroll
    for (int rt = 0; rt < NRT; ++rt) {
        float4_ acc[4];
#pragma unroll
        for (int g = 0; g < 4; ++g) {
            float b = bR[g];
            acc[g][0] = b; acc[g][1] = b; acc[g][2] = b; acc[g][3] = b;
        }
#pragma unroll
        for (int kb = 0; kb < 4; ++kb) {
            half8 ae = *(const half8*)(eA + (rt * 16 + l15) * HS + kb * 32 + q * 8);
            half8 ah = *(const half8*)(hA + (rt * 16 + l15) * HS + kb * 32 + q * 8);
#pragma unroll
            for (int g = 0; g < 4; ++g) {
                acc[g] = __builtin_amdgcn_mfma_f32_16x16x32_f16(ae, wfi[g][kb], acc[g], 0, 0, 0);
                acc[g] = __builtin_amdgcn_mfma_f32_16x16x32_f16(ah, wfh[g][kb], acc[g], 0, 0, 0);
            }
        }
        cell_update(acc, cS[rt], hOut, rt, w, q, l15);
    }
}

// e_t = relu(x_t @ encW^T + enc_b); wave w -> e cols [16w,16w+16)
__device__ __forceinline__ void enc_proj(
    const half_t* __restrict__ xa, half_t* __restrict__ eOut,
    half8 encWf, float benc, int t, int w, int q, int l15) {
    const half_t* xs = xa + (t & 1) * MTILE * XS;
#pragma unroll
    for (int rt = 0; rt < NRT; ++rt) {
        half8 af = *(const half8*)(xs + (rt * 16 + l15) * XS + q * 8);
        float4_ a;
        a[0] = benc; a[1] = benc; a[2] = benc; a[3] = benc;
        a = __builtin_amdgcn_mfma_f32_16x16x32_f16(af, encWf, a, 0, 0, 0);
#pragma unroll
        for (int r = 0; r < 4; ++r) {
            float v = a[r];
            v = v > 0.f ? v : 0.f;
            eOut[(rt * 16 + q * 4 + r) * HS + w * 16 + l15] = (half_t)v;
        }
    }
}

__global__ __launch_bounds__(512, 2) void seq2seq_main_k(
    const float* __restrict__ x,
    const float* __restrict__ enc_b,
    const float* __restrict__ fc1_b,
    const float* __restrict__ fc2_W,
    const float* __restrict__ fc2_b,
    const half_t* __restrict__ wsh,
    const float* __restrict__ be,
    const float* __restrict__ bd,
    float* __restrict__ out) {
    __shared__ __align__(16) half_t xa[XSLOTS * MTILE * XS];   // 16128 B
    __shared__ __align__(16) half_t e_lds[2][MTILE * HS];      // 62720 B
    __shared__ __align__(16) half_t h_lds[2][MTILE * HS];      // 62720 B
    __shared__ float pred_lds[4][MTILE];                       // 1792 B  -> 140 KB

    const int tid  = threadIdx.x;
    const int lane = tid & 63;
    const int w    = tid >> 6;        // wave 0..7
    const int q    = lane >> 4;
    const int l15  = lane & 15;
    const int n0   = blockIdx.x * MTILE;

    const half_t* WihE  = wsh;
    const half_t* WhhE  = wsh + 65536;
    const half_t* WihD  = wsh + 131072;
    const half_t* WhhD  = wsh + 196608;
    const half_t* encWp = wsh + 262144;
    const half_t* fc1p  = wsh + 266240;

    float beR[4], bdR[4];
#pragma unroll
    for (int g = 0; g < 4; ++g) {
        int col = g * 128 + w * 16 + l15;
        beR[g] = be[col];
        bdR[g] = bd[col];
    }
    float benc = enc_b[w * 16 + l15];

    // prime rolling x buffer with t=0,1
    stage_x(x, xa, 0, n0, tid);
    stage_x(x, xa, 1, n0, tid);

    // zero initial h
    for (int i = tid; i < MTILE * HS; i += 512) h_lds[0][i] = (half_t)0.0f;

    float c_reg[NRT][4];
#pragma unroll
    for (int rt = 0; rt < NRT; ++rt)
#pragma unroll
        for (int r = 0; r < 4; ++r) c_reg[rt][r] = 0.0f;

    // encoder weights into registers (128 VGPR/wave)
    half8 wfi[4][4], wfh[4][4];
#pragma unroll
    for (int g = 0; g < 4; ++g)
#pragma unroll
        for (int kb = 0; kb < 4; ++kb) {
            int ct = g * 8 + w;
            wfi[g][kb] = *(const half8*)(WihE + ((size_t)(ct * 4 + kb) * 64 + lane) * 8);
            wfh[g][kb] = *(const half8*)(WhhE + ((size_t)(ct * 4 + kb) * 64 + lane) * 8);
        }
    half8 encWf = *(const half8*)(encWp + (size_t)w * 512 + lane * 8);

    __syncthreads();  // xa(0,1) + h0 ready

    enc_proj(xa, e_lds[0], encWf, benc, 0, w, q, l15);
    __syncthreads();  // e0 ready

    int cur = 0;
    // ================= encoder: one barrier per iter (r4 skeleton) =================
    for (int t = 0; t < TSTEPS; ++t) {
        // issue next x-tile's global loads first (drain during MFMA)
        if (t + 2 < TSTEPS)
            stage_x(x, xa, t + 2, n0, tid);   // slot t&1: last read by proj(t) in iter t-1
        lstm_step(e_lds[t & 1], h_lds[cur], h_lds[cur ^ 1], wfi, wfh, beR, c_reg, w, q, l15);
        if (t + 1 < TSTEPS)
            enc_proj(xa, e_lds[(t + 1) & 1], encWf, benc, t + 1, w, q, l15);
        __syncthreads();
        cur ^= 1;
    }

    // ---- decoder weights overwrite encoder weights (one-time, L2-resident) ----
#pragma unroll
    for (int g = 0; g < 4; ++g)
#pragma unroll
        for (int kb = 0; kb < 4; ++kb) {
            int ct = g * 8 + w;
            wfi[g][kb] = *(const half8*)(WihD + ((size_t)(ct * 4 + kb) * 64 + lane) * 8);
            wfh[g][kb] = *(const half8*)(WhhD + ((size_t)(ct * 4 + kb) * 64 + lane) * 8);
        }
    half8 fc1f[4];
#pragma unroll
    for (int kb = 0; kb < 4; ++kb)
        fc1f[kb] = *(const half8*)(fc1p + ((size_t)((w & 3) * 4 + kb) * 64 + lane) * 8);
    float bf1 = fc1_b[(w & 3) * 16 + l15];
    float wf2 = fc2_W[(w & 3) * 16 + l15];
    float bf2 = fc2_b[0];
    const int rt0 = (w >> 2) * 4;            // head: waves 0-3 -> rt 0..3, waves 4-7 -> rt 4..6
    const int rtN = (w >> 2) ? 3 : 4;

    // d_in = final encoder h (fixed across decoder steps): copy h[cur] -> e_lds[0]
    for (int i = tid; i < MTILE * 64; i += 512) {
        int row = i >> 6, dc = i & 63;
        ((unsigned int*)(e_lds[0] + row * HS))[dc] =
            ((const unsigned int*)(h_lds[cur] + row * HS))[dc];
    }
    __syncthreads();

    // ================= decoder =================
    for (int s = 0; s < DECS; ++s) {
        lstm_step(e_lds[0], h_lds[cur], h_lds[cur ^ 1], wfi, wfh, bdR, c_reg, w, q, l15);
        cur ^= 1;
        __syncthreads();  // new h ready
        // head: o64 = relu(h @ fc1^T + b1); pred = o64 @ fc2^T + b2
#pragma unroll
        for (int rp = 0; rp < 4; ++rp) {
            if (rp < rtN) {
                int rt = rt0 + rp;
                float4_ hacc;
                hacc[0] = bf1; hacc[1] = bf1; hacc[2] = bf1; hacc[3] = bf1;
#pragma unroll
                for (int kb = 0; kb < 4; ++kb) {
                    half8 af = *(const half8*)(h_lds[cur] + (rt * 16 + l15) * HS + kb * 32 + q * 8);
                    hacc = __builtin_amdgcn_mfma_f32_16x16x32_f16(af, fc1f[kb], hacc, 0, 0, 0);
                }
#pragma unroll
                for (int r = 0; r < 4; ++r) {
                    float v = hacc[r];
                    v = v > 0.f ? v : 0.f;
                    v *= wf2;
                    v += __shfl_xor(v, 1, 64);
                    v += __shfl_xor(v, 2, 64);
                    v += __shfl_xor(v, 4, 64);
                    v += __shfl_xor(v, 8, 64);
                    if (l15 == 0) pred_lds[w & 3][rt * 16 + q * 4 + r] = v;
                }
            }
        }
        __syncthreads();
        if (tid < MTILE) {
            float sum = pred_lds[0][tid] + pred_lds[1][tid] + pred_lds[2][tid] + pred_lds[3][tid] + bf2;
            int n = n0 + tid;
            if (n < NNODES) out[(size_t)n * DECS + s] = sum;
        }
        // pred_lds(s+1) writes are ordered behind the next lstm step's barrier
    }
}

extern "C" void kernel_launch(void* const* d_in, const int* in_sizes, int n_in,
                              void* d_out, int out_size, void* d_ws, size_t ws_size,
                              hipStream_t stream) {
    (void)in_sizes; (void)n_in; (void)out_size; (void)ws_size;
    const float* x     = (const float*)d_in[0];
    const float* enc_W = (const float*)d_in[1];
    const float* enc_b = (const float*)d_in[2];
    const float* Wih_e = (const float*)d_in[3];
    const float* Whh_e = (const float*)d_in[4];
    const float* bih_e = (const float*)d_in[5];
    const float* bhh_e = (const float*)d_in[6];
    const float* Wih_d = (const float*)d_in[7];
    const float* Whh_d = (const float*)d_in[8];
    const float* bih_d = (const float*)d_in[9];
    const float* bhh_d = (const float*)d_in[10];
    const float* fc1_W = (const float*)d_in[11];
    const float* fc1_b = (const float*)d_in[12];
    const float* fc2_W = (const float*)d_in[13];
    const float* fc2_b = (const float*)d_in[14];

    half_t* wsh = (half_t*)d_ws;
    float*  be  = (float*)((char*)d_ws + WS_FLOAT_OFF);
    float*  bd  = be + 512;

    pack_weights_k<<<256, 256, 0, stream>>>(Wih_e, wsh + 0,      128, 4, 65536);
    pack_weights_k<<<256, 256, 0, stream>>>(Whh_e, wsh + 65536,  128, 4, 65536);
    pack_weights_k<<<256, 256, 0, stream>>>(Wih_d, wsh + 131072, 128, 4, 65536);
    pack_weights_k<<<256, 256, 0, stream>>>(Whh_d, wsh + 196608, 128, 4, 65536);
    pack_weights_k<<<16,  256, 0, stream>>>(enc_W, wsh + 262144, 32,  1, 4096);
    pack_weights_k<<<32,  256, 0, stream>>>(fc1_W, wsh + 266240, 128, 4, 8192);
    prep_bias_k<<<2, 256, 0, stream>>>(bih_e, bhh_e, bih_d, bhh_d, be, bd);

    seq2seq_main_k<<<NTILES, 512, 0, stream>>>(x, enc_b, fc1_b, fc2_W, fc2_b,
                                               wsh, be, bd, (float*)d_out);
}